// Round 6
// baseline (148.449 us; speedup 1.0000x reference)
//
#include <hip/hip_runtime.h>
#include <hip/hip_bf16.h>
#include <cstdint>

#define HD 128

typedef __attribute__((ext_vector_type(8))) short short8;
typedef __attribute__((ext_vector_type(4))) float f32x4;
typedef __attribute__((ext_vector_type(4))) unsigned int u32x4;

static __device__ __forceinline__ short bf16_bits(float v) {
    __hip_bfloat16 h = __float2bfloat16(v);
    return __builtin_bit_cast(short, h);
}

// ---------------------------------------------------------------------------
// Pre-cast (+ merged mask-dtype detector in block (0,0)).
// W{1,2,3}[d] (fp32, [j_in][m_out]) -> bf16 A-operand image in ws.
// Image s (= d*3+layer): 32 granule-pairs p = kb*8+tm, each a contiguous
// 1024-B block; lane l (= g*16 + r) owns bytes p*1024 + l*16 .. +15, holding
// 8 bf16 of row m = tm*16 + r with logical input index
// j = 32*kb + 16*(jj>>2) + 4*g + (jj&3)   (K-permutation: MFMA D == next B).
// Lane-ordered & contiguous => conflict-free ds_read_b128 AND linear
// global_load_lds staging.  Grid (9, 8): block = one s x 4 pairs.
// Detector: byte at 4k+1 nonzero only for a 1-byte bool upload (~50% of
// samples); int32/fp32 0.0/1.0 have zero there.
// ---------------------------------------------------------------------------
__global__ __launch_bounds__(256) void precast_kernel(
    const float* __restrict__ W1, const float* __restrict__ W2,
    const float* __restrict__ W3, const unsigned char* __restrict__ mask,
    int n_mask, char* __restrict__ ws, int* __restrict__ mflag)
{
    if (blockIdx.x == 0 && blockIdx.y == 0) {
        __shared__ int any;
        if (threadIdx.x == 0) any = 0;
        __syncthreads();
        int limit = n_mask / 4;
        if (limit > 4096) limit = 4096;
        int local = 0;
        for (int k = threadIdx.x; k < limit; k += 256)
            local |= mask[4 * k + 1];
        if (local) atomicOr(&any, 1);
        __syncthreads();
        if (threadIdx.x == 0) *mflag = any;
    }
    const int s = blockIdx.x;            // 0..8
    const int d = s / 3, li = s % 3;
    const float* W = (li == 0 ? W1 : li == 1 ? W2 : W3) + d * HD * HD;
    const int t = threadIdx.x;
    const int p = blockIdx.y * 4 + (t >> 6);   // granule pair 0..31
    const int l = t & 63;
    const int kb = p >> 3, tm = p & 7;
    const int g = l >> 4;
    const int m = tm * 16 + (l & 15);
    const int jbase = 32 * kb + 4 * g;
    unsigned int pk[4];
    #pragma unroll
    for (int w = 0; w < 4; ++w) {
        const int j0 = jbase + (w >> 1) * 16 + (w & 1) * 2;   // jj = 2w
        const float a = W[j0 * HD + m];
        const float b = W[(j0 + 1) * HD + m];
        pk[w] = (unsigned short)bf16_bits(a) |
                ((unsigned)(unsigned short)bf16_bits(b) << 16);
    }
    *reinterpret_cast<u32x4*>(ws + s * 32768 + p * 1024 + l * 16) =
        u32x4{pk[0], pk[1], pk[2], pk[3]};
}

// ---------------------------------------------------------------------------
// Stage one 32 KB weight image into the single LDS buffer (linear, 16B/lane).
// ---------------------------------------------------------------------------
static __device__ __forceinline__ void stage_img(const char* __restrict__ src,
                                                 char* dst, int tid)
{
    #pragma unroll
    for (int it = 0; it < 8; ++it)
        __builtin_amdgcn_global_load_lds(
            (const __attribute__((address_space(1))) void*)(src + it * 4096 + tid * 16),
            (__attribute__((address_space(3))) void*)(dst + it * 4096 + tid * 16),
            16, 0, 0);
}

// ---------------------------------------------------------------------------
// Main fused kernel. Block = 256 thr (4 waves); wave owns 32 rows (tc=2).
// tm-pair-outer: only one feature-pair's accumulator (16 regs) live at a
// time -> total live ~165 regs; __launch_bounds__(256,3) + 32 KB single
// LDS buffer targets 3 blocks/CU (12 waves/CU). Two barriers per layer:
// [stage done] compute [reads done] stage-next; stage bubble hidden by
// the other resident blocks.
// ---------------------------------------------------------------------------
#define MFMA16(A, B, C) __builtin_amdgcn_mfma_f32_16x16x32_bf16(A, B, C, 0, 0, 0)

// Middle layer: BSRC-fragments -> BDST-fragments, bias-init, relu, optional
// mask fold. Uses wlds, lofs, g, mkf0, mkf1 from enclosing scope.
#define LAYER_MID(BSRC, BDST, BIAS, FOLDM)                                    \
  {                                                                           \
    _Pragma("unroll")                                                         \
    for (int pm = 0; pm < 4; ++pm) {                                          \
      f32x4 aA0, aA1, aB0, aB1;                                               \
      {                                                                       \
        const f32x4 bvA = *(const f32x4*)((BIAS) + (2 * pm) * 16 + g * 4);    \
        const f32x4 bvB = *(const f32x4*)((BIAS) + (2 * pm + 1) * 16 + g * 4);\
        aA0 = bvA; aA1 = bvA; aB0 = bvB; aB1 = bvB;                           \
      }                                                                       \
      _Pragma("unroll")                                                       \
      for (int kb = 0; kb < 4; ++kb) {                                        \
        const short8 a0 = *(const short8*)(wlds + (kb * 8 + 2 * pm) * 1024 + lofs);     \
        const short8 a1 = *(const short8*)(wlds + (kb * 8 + 2 * pm + 1) * 1024 + lofs); \
        aA0 = MFMA16(a0, BSRC[kb][0], aA0);                                   \
        aA1 = MFMA16(a0, BSRC[kb][1], aA1);                                   \
        aB0 = MFMA16(a1, BSRC[kb][0], aB0);                                   \
        aB1 = MFMA16(a1, BSRC[kb][1], aB1);                                   \
      }                                                                       \
      _Pragma("unroll")                                                       \
      for (int q = 0; q < 4; ++q) {                                           \
        float vA0 = fmaxf(aA0[q], 0.f), vA1 = fmaxf(aA1[q], 0.f);             \
        float vB0 = fmaxf(aB0[q], 0.f), vB1 = fmaxf(aB1[q], 0.f);             \
        if (FOLDM) { vA0 *= mkf0; vA1 *= mkf1; vB0 *= mkf0; vB1 *= mkf1; }    \
        BDST[pm][0][q]     = bf16_bits(vA0);                                  \
        BDST[pm][0][4 + q] = bf16_bits(vB0);                                  \
        BDST[pm][1][q]     = bf16_bits(vA1);                                  \
        BDST[pm][1][4 + q] = bf16_bits(vB1);                                  \
      }                                                                       \
    }                                                                         \
  }

// Final layer: accumulate into persistent acc3 (summed over d).
#define LAYER_FIN(BSRC)                                                       \
  {                                                                           \
    _Pragma("unroll")                                                         \
    for (int pm = 0; pm < 4; ++pm) {                                          \
      _Pragma("unroll")                                                       \
      for (int kb = 0; kb < 4; ++kb) {                                        \
        const short8 a0 = *(const short8*)(wlds + (kb * 8 + 2 * pm) * 1024 + lofs);     \
        const short8 a1 = *(const short8*)(wlds + (kb * 8 + 2 * pm + 1) * 1024 + lofs); \
        acc3[2 * pm][0]     = MFMA16(a0, BSRC[kb][0], acc3[2 * pm][0]);       \
        acc3[2 * pm][1]     = MFMA16(a0, BSRC[kb][1], acc3[2 * pm][1]);       \
        acc3[2 * pm + 1][0] = MFMA16(a1, BSRC[kb][0], acc3[2 * pm + 1][0]);   \
        acc3[2 * pm + 1][1] = MFMA16(a1, BSRC[kb][1], acc3[2 * pm + 1][1]);   \
      }                                                                       \
    }                                                                         \
  }

__global__ __launch_bounds__(256, 3) void mlp_kernel(
    const float* __restrict__ x, const void* __restrict__ maskraw,
    const int* __restrict__ mflag,
    const float* __restrict__ W0, const float* __restrict__ b0,
    const float* __restrict__ b1, const float* __restrict__ b2,
    const float* __restrict__ b3, const char* __restrict__ wsWT,
    float* __restrict__ out)
{
    __shared__ char wlds[32768];
    const int tid  = threadIdx.x;
    const int wid  = tid >> 6;
    const int lane = tid & 63;
    const int r    = lane & 15;          // batch-row within c-tile (MFMA col)
    const int g    = lane >> 4;          // lane group (MFMA row-quad / k-group)
    const int lofs = lane * 16;
    const int row0 = blockIdx.x * 128 + wid * 32;
    const bool bytewise = (*mflag != 0);
    const unsigned char* mask_b = (const unsigned char*)maskraw;
    const int*           mask_w = (const int*)maskraw;

    // acc3[tm][tc][i] = out[row0+tc*16+r][tm*16+g*4+i]
    f32x4 acc3[8][2];
    #pragma unroll
    for (int tm = 0; tm < 8; ++tm)
        #pragma unroll
        for (int tc = 0; tc < 2; ++tc)
            acc3[tm][tc] = f32x4{0.f, 0.f, 0.f, 0.f};

    short8 bfA[4][2], bfB[4][2];         // h^T fragments [kb][tc]

    stage_img(wsWT, wlds, tid);          // s = 0

    for (int d = 0; d < 3; ++d) {
        const int mi0 = (row0 + r) * 3 + d;
        const int mi1 = (row0 + 16 + r) * 3 + d;
        const float xv0 = x[mi0], xv1 = x[mi1];
        const float mkf0 = (bytewise ? (mask_b[mi0] != 0) : (mask_w[mi0] != 0)) ? 1.f : 0.f;
        const float mkf1 = (bytewise ? (mask_b[mi1] != 0) : (mask_w[mi1] != 0)) ? 1.f : 0.f;

        // ---- layer 0: h0 = relu(x*W0 + b0) directly as B-fragments (VALU) ----
        {
            const float* W0d = W0 + d * HD;
            const float* b0d = b0 + d * HD;
            #pragma unroll
            for (int kb = 0; kb < 4; ++kb) {
                const f32x4 w0a = *(const f32x4*)(W0d + kb * 32 + g * 4);
                const f32x4 w0b = *(const f32x4*)(W0d + kb * 32 + 16 + g * 4);
                const f32x4 bba = *(const f32x4*)(b0d + kb * 32 + g * 4);
                const f32x4 bbb = *(const f32x4*)(b0d + kb * 32 + 16 + g * 4);
                #pragma unroll
                for (int tc = 0; tc < 2; ++tc) {
                    const float xx = tc ? xv1 : xv0;
                    short8 f;
                    #pragma unroll
                    for (int q = 0; q < 4; ++q) {
                        f[q]     = bf16_bits(fmaxf(xx * w0a[q] + bba[q], 0.f));
                        f[4 + q] = bf16_bits(fmaxf(xx * w0b[q] + bbb[q], 0.f));
                    }
                    bfA[kb][tc] = f;
                }
            }
        }

        __syncthreads();                          // W1_d staged (vmcnt drained)
        LAYER_MID(bfA, bfB, b1 + d * HD, false);  // h1 = relu(h0 @ W1 + b1)
        __syncthreads();                          // all W1 reads done
        stage_img(wsWT + (d * 3 + 1) * 32768, wlds, tid);

        __syncthreads();                          // W2_d staged
        LAYER_MID(bfB, bfA, b2 + d * HD, true);   // h2 = mask * relu(h1 @ W2 + b2)
        __syncthreads();
        stage_img(wsWT + (d * 3 + 2) * 32768, wlds, tid);

        __syncthreads();                          // W3_d staged
        LAYER_FIN(bfA);                           // acc3 += h2 @ W3
        __syncthreads();
        if (d < 2) stage_img(wsWT + (d * 3 + 3) * 32768, wlds, tid);
    }

    // ---- epilogue: + sum_d mask_d * b3_d, store fp32 float4 ----
    #pragma unroll
    for (int tc = 0; tc < 2; ++tc) {
        const int row = row0 + tc * 16 + r;
        float mk[3];
        #pragma unroll
        for (int dd = 0; dd < 3; ++dd) {
            const int mi = row * 3 + dd;
            mk[dd] = (bytewise ? (mask_b[mi] != 0) : (mask_w[mi] != 0)) ? 1.f : 0.f;
        }
        float* orow = out + (long)row * HD;
        #pragma unroll
        for (int tm = 0; tm < 8; ++tm) {
            const f32x4 ba  = *(const f32x4*)(b3 + 0 * HD + tm * 16 + g * 4);
            const f32x4 bbv = *(const f32x4*)(b3 + 1 * HD + tm * 16 + g * 4);
            const f32x4 bc  = *(const f32x4*)(b3 + 2 * HD + tm * 16 + g * 4);
            f32x4 o = acc3[tm][tc];
            #pragma unroll
            for (int q = 0; q < 4; ++q)
                o[q] += mk[0] * ba[q] + mk[1] * bbv[q] + mk[2] * bc[q];
            *reinterpret_cast<f32x4*>(orow + tm * 16 + g * 4) = o;
        }
    }
}

extern "C" void kernel_launch(void* const* d_in, const int* in_sizes, int n_in,
                              void* d_out, int out_size, void* d_ws, size_t ws_size,
                              hipStream_t stream) {
    const float* x  = (const float*)d_in[0];
    const unsigned char* mask = (const unsigned char*)d_in[1];
    const float* W0 = (const float*)d_in[2];
    const float* b0 = (const float*)d_in[3];
    const float* W1 = (const float*)d_in[4];
    const float* b1 = (const float*)d_in[5];
    const float* W2 = (const float*)d_in[6];
    const float* b2 = (const float*)d_in[7];
    const float* W3 = (const float*)d_in[8];
    const float* b3 = (const float*)d_in[9];
    float* out = (float*)d_out;
    char* ws = (char*)d_ws;               // weights: 9*32768 B, flag at +294912
    int* mflag = (int*)(ws + 9 * 32768);
    const int n_mask = in_sizes[1];       // N*D elements

    hipLaunchKernelGGL(precast_kernel, dim3(9, 8), dim3(256), 0, stream,
                       W1, W2, W3, mask, n_mask, ws, mflag);
    hipLaunchKernelGGL(mlp_kernel, dim3(1024), dim3(256), 0, stream,
                       x, (const void*)mask, mflag, W0, b0, b1, b2, b3, ws, out);
}